// Round 1
// baseline (357.948 us; speedup 1.0000x reference)
//
#include <hip/hip_runtime.h>
#include <math.h>

#define PI_F 3.14159265358979323846f

// LDS layout: 145 rows x 33 float4 (row stride 528 B) = 76560 B.
//   rows 0..7    : zeros (top halo)
//   rows 8..135  : data rows 0..127 in cols 0..31; col 32 = zero (col sentinel)
//   rows 136..144: zeros (bottom halo; also the all-OOB 9-row sentinel window)
// Per-tap unsigned-min clamps map every OOB case onto zero regions, so the
// 9-row inner loop is 18 ds_read_b128 with immediate offsets off two base
// registers -- ZERO per-read bounds/address VALU.
// Max address: row 144 (pr=136,k=8), col 32: 144*528 + 32*16 + 16 = 76560 ✓.

__device__ __forceinline__ unsigned umin32(unsigned a, unsigned b) { return a < b ? a : b; }

__device__ __forceinline__ void ld8k(float (&D)[8], const char* Lb,
                                     unsigned a0, unsigned a1, int koff) {
  float4 q0 = *(const float4*)(Lb + a0 + koff);   // koff folds into ds_read offset imm
  float4 q1 = *(const float4*)(Lb + a1 + koff);
  D[0] = q0.x; D[1] = q0.y; D[2] = q0.z; D[3] = q0.w;
  D[4] = q1.x; D[5] = q1.y; D[6] = q1.z; D[7] = q1.w;
}

template <int R>
__device__ __forceinline__ void tap4(float4& a, const float (&T)[8], const float (&B)[8],
                                     float w00, float w01, float w10, float w11) {
  a.x = fmaf(w00, T[R + 0], fmaf(w01, T[R + 1], fmaf(w10, B[R + 0], fmaf(w11, B[R + 1], a.x))));
  a.y = fmaf(w00, T[R + 1], fmaf(w01, T[R + 2], fmaf(w10, B[R + 1], fmaf(w11, B[R + 2], a.y))));
  a.z = fmaf(w00, T[R + 2], fmaf(w01, T[R + 3], fmaf(w10, B[R + 2], fmaf(w11, B[R + 3], a.z))));
  a.w = fmaf(w00, T[R + 3], fmaf(w01, T[R + 4], fmaf(w10, B[R + 3], fmaf(w11, B[R + 4], a.w))));
}

template <int R>
__device__ __forceinline__ void kloopP(float4 (&acc)[8], const char* Lb,
                                       unsigned a0, unsigned a1,
                                       float w00, float w01, float w10, float w11) {
  float A[8], Bf[8];
  ld8k(A, Lb, a0, a1, 0);
#pragma unroll
  for (int kk = 0; kk < 4; kk++) {
    ld8k(Bf, Lb, a0, a1, (2 * kk + 1) * 528);
    tap4<R>(acc[2 * kk + 0], A, Bf, w00, w01, w10, w11);
    ld8k(A, Lb, a0, a1, (2 * kk + 2) * 528);
    tap4<R>(acc[2 * kk + 1], Bf, A, w00, w01, w10, w11);
  }
}

__global__ __launch_bounds__(512, 4)
void pgd_main_kernel(const float* __restrict__ X,
                     const float* __restrict__ offx, const float* __restrict__ offy,
                     const float* __restrict__ ua, const float* __restrict__ us,
                     const float* __restrict__ araw, const float* __restrict__ sraw,
                     float* __restrict__ out) {
  __shared__ float4 L[4785];   // 145 * 33 quads = 76560 B (gfx950: 160 KB LDS/CU, 2 blocks/CU)
  int p = blockIdx.x;          // plane = b*128 + o*4 + c
  int o = (p & 127) >> 2;
  const float4* __restrict__ xg = (const float4*)(X + (size_t)p * 16384);
  int tid = threadIdx.x;

  // ---- zero the 689 pad quads (disjoint from the data quads -> one barrier) ----
  const float4 z4 = make_float4(0.f, 0.f, 0.f, 0.f);
  for (int i = tid; i < 689; i += 512) {
    int q = (i < 264) ? i                                    // rows 0..7 (8*33 quads)
          : (i < 561) ? (4488 + (i - 264))                   // rows 136..144 (9*33)
          : ((8 + (i - 561)) * 33 + 32);                     // col 32 of data rows
    L[q] = z4;
  }

  // ---- stage the plane: data row d -> LDS row d+8, cols 0..31 ----
#pragma unroll
  for (int i = 0; i < 8; i++) {
    int gq = tid + i * 512;
    L[((gq >> 5) + 8) * 33 + (gq & 31)] = xg[gq];
  }

  // ---- per-wave tap params (overlaps with staging) ----
  int lane = tid & 63;
  int t = lane & 15;
  const float MIN_A = 0.024979197860971382f;   // atan2(0.5,10)/2
  const float MAX_A = PI_F;
  const float MIN_S = 0.2f, MAX_S = 5.0f;
  const float EPS = 1.1920928955078125e-07f;   // np.float32 eps

  float angle_std = 1.0f / (1.0f + expf(-araw[o])) * (MAX_A - MIN_A) + MIN_A;
  float scale_std = 1.0f / (1.0f + expf(-sraw[o])) * (MAX_S - MIN_S) + MIN_S;
  float high_a = fminf(angle_std * 3.0f, PI_F);
  float s3 = scale_std * 3.0f;
  float va = angle_std * angle_std + EPS;
  float vs = scale_std * scale_std + EPS;

  float denom = 0.0f;
  for (int j = 0; j < 32; j++) {
    float a = ua[o * 32 + j] * high_a;
    float s = us[o * 32 + j] * s3;
    denom += expf(-(a * a) * 0.5f / va - (s * s) * 0.5f / vs);
  }
  denom += EPS;

  float a_t = ua[o * 32 + t] * high_a;
  float s_t = us[o * 32 + t] * s3;
  float wt = expf(-(a_t * a_t) * 0.5f / va - (s_t * s_t) * 0.5f / vs) / denom * 2.0f;

  float oxv = offx[o], oyv = offy[o];
  float dist = sqrtf(oxv * oxv + oyv * oyv);
  float ang0 = atan2f(oyv, oxv);
  float ndv = dist + s_t;
  float nav = ang0 + a_t;
  float dxv = ndv * cosf(nav);
  float dyv = ndv * sinf(nav);
  float fxv = floorf(dxv), fyv = floorf(dyv);
  float axv = dxv - fxv, ayv = dyv - fyv;
  int ixL = (int)fxv;   // exact: already floored
  int iyL = (int)fyv;
  float w00L = wt * (1.0f - ayv) * (1.0f - axv);
  float w01L = wt * (1.0f - ayv) * axv;
  float w10L = wt * ayv * (1.0f - axv);
  float w11L = wt * ayv * axv;

  __syncthreads();

  int wv = tid >> 6;        // 0..7
  int half = lane >> 5;     // 0..1
  int c = lane & 31;        // float4 output chunk: cols 4c..4c+3
  int g = wv * 2 + half;    // row-group 0..15
  int y0 = g * 8;           // 8 output rows y0..y0+7
  int y08 = y0 + 8;         // padded-row bias
  int c4 = 4 * c;
  const char* Lb = (const char*)L;
  float* outp = out + (size_t)p * 16384;

  float4 acc[8];
#pragma unroll
  for (int k = 0; k < 8; k++) acc[k] = make_float4(0.f, 0.f, 0.f, 0.f);

  for (int tt = 0; tt < 16; tt++) {
    // broadcast tap tt's params from lane tt (wave-uniform -> SGPRs)
    float w00 = __uint_as_float(__builtin_amdgcn_readlane(__float_as_uint(w00L), tt));
    float w01 = __uint_as_float(__builtin_amdgcn_readlane(__float_as_uint(w01L), tt));
    float w10 = __uint_as_float(__builtin_amdgcn_readlane(__float_as_uint(w10L), tt));
    float w11 = __uint_as_float(__builtin_amdgcn_readlane(__float_as_uint(w11L), tt));
    int ix = __builtin_amdgcn_readlane(ixL, tt);
    int iy = __builtin_amdgcn_readlane(iyL, tt);

    int b0 = (c4 + ix) >> 2;                       // leftmost needed input quad (floor)
    int r = ix & 3;                                // wave-uniform sub-word alignment
    // k-invariant clamps: any OOB row-window/col lands on a zero region.
    unsigned c0 = umin32((unsigned)b0, 32u);       // negative -> huge -> 32 (zero col)
    unsigned c1 = umin32((unsigned)(b0 + 1), 32u);
    unsigned pr = umin32((unsigned)(y08 + iy), 136u); // <0 -> huge -> 136 (zero window)
    unsigned base = pr * 528u;
    unsigned a0 = base + c0 * 16u;
    unsigned a1 = base + c1 * 16u;

    switch (r) {
      case 0: kloopP<0>(acc, Lb, a0, a1, w00, w01, w10, w11); break;
      case 1: kloopP<1>(acc, Lb, a0, a1, w00, w01, w10, w11); break;
      case 2: kloopP<2>(acc, Lb, a0, a1, w00, w01, w10, w11); break;
      default: kloopP<3>(acc, Lb, a0, a1, w00, w01, w10, w11); break;
    }
  }

#pragma unroll
  for (int k = 0; k < 8; k++) {
    *(float4*)(outp + (size_t)(y0 + k) * 128 + 4 * c) = acc[k];
  }
}

extern "C" void kernel_launch(void* const* d_in, const int* in_sizes, int n_in,
                              void* d_out, int out_size, void* d_ws, size_t ws_size,
                              hipStream_t stream) {
  const float* x  = (const float*)d_in[0];
  const float* ox = (const float*)d_in[1];
  const float* oy = (const float*)d_in[2];
  const float* ua = (const float*)d_in[3];
  const float* us = (const float*)d_in[4];
  const float* ar = (const float*)d_in[5];
  const float* sr = (const float*)d_in[6];
  float* out = (float*)d_out;
  (void)d_ws; (void)ws_size; (void)in_sizes; (void)n_in; (void)out_size;

  hipLaunchKernelGGL(pgd_main_kernel, dim3(2048), dim3(512), 0, stream,
                     x, ox, oy, ua, us, ar, sr, out);
}

// Round 2
// 357.500 us; speedup vs baseline: 1.0013x; 1.0013x over previous
//
#include <hip/hip_runtime.h>
#include <math.h>

#define PI_F 3.14159265358979323846f

// LDS layout: 145 rows x 32 float4 (row stride 512 B) = 74240 B.
//   rows 0..7    : zeros (top halo)
//   rows 8..135  : data rows 0..127
//   rows 136..144: zeros (bottom halo + all-OOB 9-row sentinel window)
// 512 B stride keeps every row bank-identical (measured: ~5 conflict cyc/read
// vs 12.4 for the 528 B stride of R1). Row OOB: k-invariant unsigned-min clamp
// onto the zero window. Column OOB: k-invariant per-lane select redirecting the
// address into the zero window (costs ~6 VALU per tap, amortized over 18 reads).
// Inner loop: 18 ds_read_b128 with immediate offsets off two base registers.
// Max address: 136*512 + 31*16 + 8*512 + 16 = 74240 ✓.

__device__ __forceinline__ unsigned umin32(unsigned a, unsigned b) { return a < b ? a : b; }

__device__ __forceinline__ void ld8k(float (&D)[8], const char* Lb,
                                     unsigned a0, unsigned a1, int koff) {
  float4 q0 = *(const float4*)(Lb + a0 + koff);   // koff folds into ds_read offset imm
  float4 q1 = *(const float4*)(Lb + a1 + koff);
  D[0] = q0.x; D[1] = q0.y; D[2] = q0.z; D[3] = q0.w;
  D[4] = q1.x; D[5] = q1.y; D[6] = q1.z; D[7] = q1.w;
}

template <int R>
__device__ __forceinline__ void tap4(float4& a, const float (&T)[8], const float (&B)[8],
                                     float w00, float w01, float w10, float w11) {
  a.x = fmaf(w00, T[R + 0], fmaf(w01, T[R + 1], fmaf(w10, B[R + 0], fmaf(w11, B[R + 1], a.x))));
  a.y = fmaf(w00, T[R + 1], fmaf(w01, T[R + 2], fmaf(w10, B[R + 1], fmaf(w11, B[R + 2], a.y))));
  a.z = fmaf(w00, T[R + 2], fmaf(w01, T[R + 3], fmaf(w10, B[R + 2], fmaf(w11, B[R + 3], a.z))));
  a.w = fmaf(w00, T[R + 3], fmaf(w01, T[R + 4], fmaf(w10, B[R + 3], fmaf(w11, B[R + 4], a.w))));
}

template <int R>
__device__ __forceinline__ void kloopP(float4 (&acc)[8], const char* Lb,
                                       unsigned a0, unsigned a1,
                                       float w00, float w01, float w10, float w11) {
  float A[8], Bf[8];
  ld8k(A, Lb, a0, a1, 0);
#pragma unroll
  for (int kk = 0; kk < 4; kk++) {
    ld8k(Bf, Lb, a0, a1, (2 * kk + 1) * 512);
    tap4<R>(acc[2 * kk + 0], A, Bf, w00, w01, w10, w11);
    ld8k(A, Lb, a0, a1, (2 * kk + 2) * 512);
    tap4<R>(acc[2 * kk + 1], Bf, A, w00, w01, w10, w11);
  }
}

__global__ __launch_bounds__(512, 4)
void pgd_main_kernel(const float* __restrict__ X,
                     const float* __restrict__ offx, const float* __restrict__ offy,
                     const float* __restrict__ ua, const float* __restrict__ us,
                     const float* __restrict__ araw, const float* __restrict__ sraw,
                     float* __restrict__ out) {
  __shared__ float4 L[4640];   // 145 * 32 quads = 74240 B -> 2 blocks/CU
  int p = blockIdx.x;          // plane = b*128 + o*4 + c
  int o = (p & 127) >> 2;
  const float4* __restrict__ xg = (const float4*)(X + (size_t)p * 16384);
  int tid = threadIdx.x;

  // ---- zero the 544 pad quads (rows 0..7 and 136..144) ----
  const float4 z4 = make_float4(0.f, 0.f, 0.f, 0.f);
  {
    int i = tid;
    L[(i < 256) ? i : (4352 + (i - 256))] = z4;   // covers 512 of 544
    if (tid < 32) L[4352 + 256 + tid] = z4;       // remaining 32
  }

  // ---- stage the plane: data quad gq -> LDS quad gq+256 (fully contiguous) ----
#pragma unroll
  for (int i = 0; i < 8; i++) {
    int gq = tid + i * 512;
    L[gq + 256] = xg[gq];
  }

  // ---- per-wave tap params (overlaps with staging) ----
  int lane = tid & 63;
  int t = lane & 15;
  const float MIN_A = 0.024979197860971382f;   // atan2(0.5,10)/2
  const float MAX_A = PI_F;
  const float MIN_S = 0.2f, MAX_S = 5.0f;
  const float EPS = 1.1920928955078125e-07f;   // np.float32 eps

  float angle_std = 1.0f / (1.0f + expf(-araw[o])) * (MAX_A - MIN_A) + MIN_A;
  float scale_std = 1.0f / (1.0f + expf(-sraw[o])) * (MAX_S - MIN_S) + MIN_S;
  float high_a = fminf(angle_std * 3.0f, PI_F);
  float s3 = scale_std * 3.0f;
  float va = angle_std * angle_std + EPS;
  float vs = scale_std * scale_std + EPS;

  float denom = 0.0f;
  for (int j = 0; j < 32; j++) {
    float a = ua[o * 32 + j] * high_a;
    float s = us[o * 32 + j] * s3;
    denom += expf(-(a * a) * 0.5f / va - (s * s) * 0.5f / vs);
  }
  denom += EPS;

  float a_t = ua[o * 32 + t] * high_a;
  float s_t = us[o * 32 + t] * s3;
  float wt = expf(-(a_t * a_t) * 0.5f / va - (s_t * s_t) * 0.5f / vs) / denom * 2.0f;

  float oxv = offx[o], oyv = offy[o];
  float dist = sqrtf(oxv * oxv + oyv * oyv);
  float ang0 = atan2f(oyv, oxv);
  float ndv = dist + s_t;
  float nav = ang0 + a_t;
  float dxv = ndv * cosf(nav);
  float dyv = ndv * sinf(nav);
  float fxv = floorf(dxv), fyv = floorf(dyv);
  float axv = dxv - fxv, ayv = dyv - fyv;
  int ixL = (int)fxv;   // exact: already floored
  int iyL = (int)fyv;
  float w00L = wt * (1.0f - ayv) * (1.0f - axv);
  float w01L = wt * (1.0f - ayv) * axv;
  float w10L = wt * ayv * (1.0f - axv);
  float w11L = wt * ayv * axv;

  __syncthreads();

  int wv = tid >> 6;        // 0..7
  int half = lane >> 5;     // 0..1
  int c = lane & 31;        // float4 output chunk: cols 4c..4c+3
  int g = wv * 2 + half;    // row-group 0..15
  int y0 = g * 8;           // 8 output rows y0..y0+7
  int y08 = y0 + 8;         // padded-row bias
  int c4 = 4 * c;
  const char* Lb = (const char*)L;
  float* outp = out + (size_t)p * 16384;

  float4 acc[8];
#pragma unroll
  for (int k = 0; k < 8; k++) acc[k] = make_float4(0.f, 0.f, 0.f, 0.f);

  const unsigned ZOFF = 69632u;   // row 136, quad 0: start of the 9-row zero window

  for (int tt = 0; tt < 16; tt++) {
    // broadcast tap tt's params from lane tt (wave-uniform -> SGPRs)
    float w00 = __uint_as_float(__builtin_amdgcn_readlane(__float_as_uint(w00L), tt));
    float w01 = __uint_as_float(__builtin_amdgcn_readlane(__float_as_uint(w01L), tt));
    float w10 = __uint_as_float(__builtin_amdgcn_readlane(__float_as_uint(w10L), tt));
    float w11 = __uint_as_float(__builtin_amdgcn_readlane(__float_as_uint(w11L), tt));
    int ix = __builtin_amdgcn_readlane(ixL, tt);
    int iy = __builtin_amdgcn_readlane(iyL, tt);

    int b0 = (c4 + ix) >> 2;                       // leftmost needed input quad (floor)
    int r = ix & 3;                                // wave-uniform sub-word alignment
    // k-invariant row clamp: OOB window lands on the zero rows.
    unsigned pr = umin32((unsigned)(y08 + iy), 136u);
    unsigned base = pr << 9;                       // *512
    // k-invariant per-lane column selects (negative -> huge unsigned -> OOB).
    unsigned a0 = ((unsigned)b0 < 32u) ? (base + (unsigned)b0 * 16u) : ZOFF;
    unsigned a1 = ((unsigned)(b0 + 1) < 32u) ? (base + (unsigned)(b0 + 1) * 16u) : ZOFF;

    switch (r) {
      case 0: kloopP<0>(acc, Lb, a0, a1, w00, w01, w10, w11); break;
      case 1: kloopP<1>(acc, Lb, a0, a1, w00, w01, w10, w11); break;
      case 2: kloopP<2>(acc, Lb, a0, a1, w00, w01, w10, w11); break;
      default: kloopP<3>(acc, Lb, a0, a1, w00, w01, w10, w11); break;
    }
  }

#pragma unroll
  for (int k = 0; k < 8; k++) {
    *(float4*)(outp + (size_t)(y0 + k) * 128 + 4 * c) = acc[k];
  }
}

extern "C" void kernel_launch(void* const* d_in, const int* in_sizes, int n_in,
                              void* d_out, int out_size, void* d_ws, size_t ws_size,
                              hipStream_t stream) {
  const float* x  = (const float*)d_in[0];
  const float* ox = (const float*)d_in[1];
  const float* oy = (const float*)d_in[2];
  const float* ua = (const float*)d_in[3];
  const float* us = (const float*)d_in[4];
  const float* ar = (const float*)d_in[5];
  const float* sr = (const float*)d_in[6];
  float* out = (float*)d_out;
  (void)d_ws; (void)ws_size; (void)in_sizes; (void)n_in; (void)out_size;

  hipLaunchKernelGGL(pgd_main_kernel, dim3(2048), dim3(512), 0, stream,
                     x, ox, oy, ua, us, ar, sr, out);
}